// Round 4
// baseline (987.328 us; speedup 1.0000x reference)
//
#include <hip/hip_runtime.h>
#include <hip/hip_cooperative_groups.h>

namespace cg = cooperative_groups;

#define BB 16
#define SS 8192
#define DD 256

typedef __attribute__((ext_vector_type(8))) short bf16x8;
typedef __attribute__((ext_vector_type(4))) short bf16x4;
typedef __attribute__((ext_vector_type(4))) float f32x4;

__device__ __forceinline__ unsigned short f2bf(float f) {
    union { float f; unsigned u; } v; v.f = f;
    unsigned r = v.u + 0x7FFFu + ((v.u >> 16) & 1u);   // round-to-nearest-even
    return (unsigned short)(r >> 16);
}
__device__ __forceinline__ float bf2f(unsigned short u) {
    union { unsigned u; float f; } cv; cv.u = (unsigned)u << 16; return cv.f;
}
__device__ __forceinline__ unsigned pack2(float a, float b) {
    return (unsigned)f2bf(a) | ((unsigned)f2bf(b) << 16);
}
// split w into hi+lo bf16 (residual ~2^-18 relative)
__device__ __forceinline__ void split_bf(float w, unsigned short& hi, unsigned short& lo) {
    hi = f2bf(w);
    lo = f2bf(w - bf2f(hi));
}

#define LTS 40   // slab row stride in shorts: 80B = 16B*5 -> aligned b128 frag reads

// ---------------------------------------------------------------------------
// moment: partial[kc][b][d][e] = sum_{s in kc-chunk} x[b,s,d]*x[b,s,e]  (bf16 MFMA)
// plus per-(kc,b) column sums written non-atomically to sumx8 (no memset needed).
// Grid (8 kc, 2 nh, 16 b) x 512 threads. 8 waves, double-buffered LDS slab,
// register prefetch 2 steps ahead, one barrier per K-step. (unchanged, passing)
// ---------------------------------------------------------------------------
__global__ __launch_bounds__(512) void moment_kernel(const float* __restrict__ x,
                                                     float* __restrict__ partial,
                                                     float* __restrict__ sumx8) {
    const int kc = blockIdx.x;
    const int nh = blockIdx.y;
    const int b  = blockIdx.z;
    const float* xb = x + ((size_t)b * SS + (size_t)kc * 1024) * DD;

    __shared__ unsigned short Lt0[256 * LTS];
    __shared__ unsigned short Lt1[256 * LTS];
    __shared__ float csh[8 * 256];

    const int tid  = threadIdx.x;
    const int wave = tid >> 6;
    const int lane = tid & 63;
    const int lc   = lane & 15;
    const int lq   = lane >> 4;

    const int mrow0 = (wave & 3) * 64;
    const int ncol0 = nh * 128 + (wave >> 2) * 64;

    const int sg = tid >> 6;
    const int dg = tid & 63;
    const float* xt = xb + (size_t)(sg * 4) * DD + dg;

    f32x4 acc[4][4];
#pragma unroll
    for (int mi = 0; mi < 4; ++mi)
#pragma unroll
        for (int ni = 0; ni < 4; ++ni) acc[mi][ni] = (f32x4){0.f, 0.f, 0.f, 0.f};
    float cs[4] = {0.f, 0.f, 0.f, 0.f};

    float va[16], vb[16];

    auto LOAD = [&](float* v, int t) {
#pragma unroll
        for (int i = 0; i < 4; ++i)
#pragma unroll
            for (int j = 0; j < 4; ++j)
                v[i * 4 + j] = xt[(size_t)(t * 32 + i) * DD + 64 * j];
    };
    auto STAGE = [&](const float* v, unsigned short* Lw) {
        if (nh == 0) {
#pragma unroll
            for (int j = 0; j < 4; ++j)
                cs[j] += v[j] + v[4 + j] + v[8 + j] + v[12 + j];
        }
#pragma unroll
        for (int j = 0; j < 4; ++j) {
            uint2 w;
            w.x = pack2(v[j], v[4 + j]);
            w.y = pack2(v[8 + j], v[12 + j]);
            *(uint2*)&Lw[(dg + 64 * j) * LTS + sg * 4] = w;
        }
    };
    auto COMPUTE = [&](const unsigned short* Lr) {
        bf16x8 af[4], bfr[4];
#pragma unroll
        for (int mi = 0; mi < 4; ++mi)
            af[mi] = *(const bf16x8*)&Lr[(mrow0 + mi * 16 + lc) * LTS + lq * 8];
#pragma unroll
        for (int ni = 0; ni < 4; ++ni)
            bfr[ni] = *(const bf16x8*)&Lr[(ncol0 + ni * 16 + lc) * LTS + lq * 8];
#pragma unroll
        for (int mi = 0; mi < 4; ++mi)
#pragma unroll
            for (int ni = 0; ni < 4; ++ni)
                acc[mi][ni] = __builtin_amdgcn_mfma_f32_16x16x32_bf16(
                    af[mi], bfr[ni], acc[mi][ni], 0, 0, 0);
    };

    LOAD(va, 0);
    STAGE(va, Lt0);
    LOAD(vb, 1);
    __syncthreads();

    for (int tt = 0; tt < 16; ++tt) {
        const int t0 = 2 * tt;
        STAGE(vb, Lt1);
        if (t0 < 30) LOAD(va, t0 + 2);
        COMPUTE(Lt0);
        __syncthreads();
        if (t0 + 1 < 31) STAGE(va, Lt0);
        if (t0 + 1 < 30) LOAD(vb, t0 + 3);
        COMPUTE(Lt1);
        __syncthreads();
    }

    float* pp = partial + (size_t)(kc * 16 + b) * DD * DD;
#pragma unroll
    for (int mi = 0; mi < 4; ++mi)
#pragma unroll
        for (int ni = 0; ni < 4; ++ni) {
            const int row = mrow0 + mi * 16 + lq * 4;
            const int col = ncol0 + ni * 16 + lc;
#pragma unroll
            for (int r = 0; r < 4; ++r)
                pp[(size_t)(row + r) * DD + col] = acc[mi][ni][r];
        }

    if (nh == 0) {
        __syncthreads();
#pragma unroll
        for (int j = 0; j < 4; ++j) csh[sg * 256 + dg + 64 * j] = cs[j];
        __syncthreads();
        if (tid < 256) {
            float t0 = 0.f;
#pragma unroll
            for (int g = 0; g < 8; ++g) t0 += csh[g * 256 + tid];
            sumx8[(size_t)(kc * 16 + b) * DD + tid] = t0;
        }
    }
}

// ---------------------------------------------------------------------------
// stats (unchanged)
// ---------------------------------------------------------------------------
__global__ __launch_bounds__(256) void stats_kernel(const float* __restrict__ partial,
                                                    const float* __restrict__ sumx8,
                                                    float* __restrict__ m,
                                                    float* __restrict__ trbuf) {
    const int b = blockIdx.x;
    const int d = threadIdx.x;
    float sx = 0.f;
#pragma unroll
    for (int kc = 0; kc < 8; ++kc)
        sx += sumx8[(size_t)(kc * 16 + b) * DD + d];
    const float mean = sx * (1.0f / (float)SS);
    m[b * DD + d] = mean;
    float ds = 0.f;
#pragma unroll
    for (int kc = 0; kc < 8; ++kc)
        ds += partial[((size_t)(kc * 16 + b) * DD + d) * DD + d];
    const float diag = (ds - (float)SS * mean * mean) * (1.0f / (float)(SS - 1));
    __shared__ float red[256];
    red[d] = diag;
    __syncthreads();
    for (int off = 128; off > 0; off >>= 1) {
        if (d < off) red[d] += red[d + off];
        __syncthreads();
    }
    if (d == 0) {
        const float tr = red[0];
        trbuf[b]      = tr;
        trbuf[16 + b] = rsqrtf(tr);
        trbuf[32 + b] = 1.0f / tr;
    }
}

// ---------------------------------------------------------------------------
// sigman (unchanged)
// ---------------------------------------------------------------------------
__global__ __launch_bounds__(256) void sigman_kernel(const float* __restrict__ partial,
                                                     const float* __restrict__ m,
                                                     const float* __restrict__ trbuf,
                                                     float* __restrict__ Xa) {
    const int b = blockIdx.y;
    const int d = blockIdx.x;
    const int e = threadIdx.x;
    const float itr = trbuf[32 + b];
    const float md = m[b * DD + d];
    const float me = m[b * DD + e];
    float s = 0.f;
#pragma unroll
    for (int kc = 0; kc < 8; ++kc)
        s += partial[((size_t)(kc * 16 + b) * DD + d) * DD + e];
    Xa[(size_t)b * DD * DD + (size_t)d * DD + e] =
        (s - (float)SS * md * me) * (1.0f / (float)(SS - 1)) * itr;
}

// ---------------------------------------------------------------------------
// NS chain as ONE cooperative kernel: 9 product passes (7 stages, 2 fused pairs
// unrolled) separated by grid.sync() instead of 7 stream launches.
// Per pass: C = opA(A)@opB(B), split-bf16 hi/lo 3-MFMA fp32 emulation (same
// numerics as the round-3 bmm_mfma, which passed). 256 blocks x 512 thr,
// 72 KB LDS -> 1 block/CU co-resident (cooperative requirement satisfied),
// 8 waves (2/SIMD), wave tile 32x16, dbuf LDS + register prefetch.
// ---------------------------------------------------------------------------
#define BTS 72   // slab stride in shorts: 144B = 16B*9 -> aligned b128, 2-way banks
__device__ __forceinline__ void bmm_pass(const float* Ag, const float* Bg, float* Cg,
                                         int TA, int TB, int tile,
                                         unsigned short* sm) {
    const int tid  = threadIdx.x;
    const int wave = tid >> 6;
    const int lane = tid & 63;
    const int lc = lane & 15, lq = lane >> 4;
    const int m0 = (tile >> 2) * 64, n0 = (tile & 3) * 64;
    const int mrow0 = (wave & 1) * 32;
    const int ncol0 = (wave >> 1) * 16;

    const int r  = tid >> 3;         // 0..63 slab row
    const int k8 = (tid & 7) * 8;    // 8 consecutive k per thread
    const float* Arow = Ag + (size_t)(m0 + r) * DD + k8;
    const float* Brow = Bg + (size_t)(n0 + r) * DD + k8;

    unsigned short* SL[2][4];
#pragma unroll
    for (int bf = 0; bf < 2; ++bf)
#pragma unroll
        for (int w = 0; w < 4; ++w) SL[bf][w] = sm + (size_t)(bf * 4 + w) * 64 * BTS;
    // order: 0=Ahi 1=Alo 2=Bhi 3=Blo

    f32x4 acc[2];
    acc[0] = (f32x4){0.f, 0.f, 0.f, 0.f};
    acc[1] = (f32x4){0.f, 0.f, 0.f, 0.f};

    float4 a0[2], b0[2], a1[2], b1[2];

    auto LOADC = [&](float4* a, float4* b, int c) {
        a[0] = *(const float4*)(Arow + c * 64);
        a[1] = *(const float4*)(Arow + c * 64 + 4);
        b[0] = *(const float4*)(Brow + c * 64);
        b[1] = *(const float4*)(Brow + c * 64 + 4);
    };
    auto STAGE1 = [&](const float4* v, unsigned short* Shi, unsigned short* Slo,
                      int c, int gmn, int tf) {
        const float* vf = (const float*)v;
        unsigned short h[8], l[8];
#pragma unroll
        for (int j = 0; j < 8; ++j) {
            float wv = vf[j];
            if (tf) {
                const int gk = c * 64 + k8 + j;
                wv = ((gk == gmn) ? 1.5f : 0.0f) - 0.5f * wv;
            }
            split_bf(wv, h[j], l[j]);
        }
        uint4 uh, ul;
        uh.x = (unsigned)h[0] | ((unsigned)h[1] << 16);
        uh.y = (unsigned)h[2] | ((unsigned)h[3] << 16);
        uh.z = (unsigned)h[4] | ((unsigned)h[5] << 16);
        uh.w = (unsigned)h[6] | ((unsigned)h[7] << 16);
        ul.x = (unsigned)l[0] | ((unsigned)l[1] << 16);
        ul.y = (unsigned)l[2] | ((unsigned)l[3] << 16);
        ul.z = (unsigned)l[4] | ((unsigned)l[5] << 16);
        ul.w = (unsigned)l[6] | ((unsigned)l[7] << 16);
        *(uint4*)&Shi[r * BTS + k8] = uh;
        *(uint4*)&Slo[r * BTS + k8] = ul;
    };
    auto STAGE = [&](const float4* a, const float4* b, int c, int bf) {
        STAGE1(a, SL[bf][0], SL[bf][1], c, m0 + r, TA);
        STAGE1(b, SL[bf][2], SL[bf][3], c, n0 + r, TB);
    };
    auto COMPUTE = [&](int bf) {
#pragma unroll
        for (int ks = 0; ks < 2; ++ks) {
            const int ko = ks * 32 + lq * 8;
            bf16x8 ah0 = *(const bf16x8*)&SL[bf][0][(mrow0 + lc) * BTS + ko];
            bf16x8 ah1 = *(const bf16x8*)&SL[bf][0][(mrow0 + 16 + lc) * BTS + ko];
            bf16x8 al0 = *(const bf16x8*)&SL[bf][1][(mrow0 + lc) * BTS + ko];
            bf16x8 al1 = *(const bf16x8*)&SL[bf][1][(mrow0 + 16 + lc) * BTS + ko];
            bf16x8 bh  = *(const bf16x8*)&SL[bf][2][(ncol0 + lc) * BTS + ko];
            bf16x8 bl  = *(const bf16x8*)&SL[bf][3][(ncol0 + lc) * BTS + ko];
            acc[0] = __builtin_amdgcn_mfma_f32_16x16x32_bf16(al0, bh, acc[0], 0, 0, 0);
            acc[0] = __builtin_amdgcn_mfma_f32_16x16x32_bf16(ah0, bl, acc[0], 0, 0, 0);
            acc[0] = __builtin_amdgcn_mfma_f32_16x16x32_bf16(ah0, bh, acc[0], 0, 0, 0);
            acc[1] = __builtin_amdgcn_mfma_f32_16x16x32_bf16(al1, bh, acc[1], 0, 0, 0);
            acc[1] = __builtin_amdgcn_mfma_f32_16x16x32_bf16(ah1, bl, acc[1], 0, 0, 0);
            acc[1] = __builtin_amdgcn_mfma_f32_16x16x32_bf16(ah1, bh, acc[1], 0, 0, 0);
        }
    };

    LOADC(a0, b0, 0);
    STAGE(a0, b0, 0, 0);
    LOADC(a1, b1, 1);
    __syncthreads();
#pragma unroll
    for (int cc = 0; cc < 2; ++cc) {
        const int c0 = 2 * cc;
        STAGE(a1, b1, c0 + 1, 1);
        if (c0 + 2 < 4) LOADC(a0, b0, c0 + 2);
        COMPUTE(0);
        __syncthreads();
        if (c0 + 2 < 4) STAGE(a0, b0, c0 + 2, 0);
        if (c0 + 3 < 4) LOADC(a1, b1, c0 + 3);
        COMPUTE(1);
        __syncthreads();
    }

#pragma unroll
    for (int mi = 0; mi < 2; ++mi) {
        const int row = m0 + mrow0 + mi * 16 + lq * 4;
        const int col = n0 + ncol0 + lc;
#pragma unroll
        for (int rr = 0; rr < 4; ++rr)
            Cg[(size_t)(row + rr) * DD + col] = acc[mi][rr];
    }
}

__global__ __launch_bounds__(512) void ns_chain(float* Xa, float* Xb, float* T,
                                                float* Pa, float* Pb) {
    cg::grid_group grid = cg::this_grid();
    __shared__ __align__(16) unsigned short sm[8 * 64 * BTS];   // 73728 B

    const int bx   = blockIdx.x;
    const int tile = bx & 15;
    const size_t off = (size_t)(bx >> 4) * DD * DD;

    // X_{k+1} = X_k W_k^2, P_{k+1} = P_k W_k, W = 1.5I - 0.5X (all symmetric):
    // p0 T=W(Xa)^2; p1 Xb=Xa*T; p2 Pa=W(Xa)W(Xb); p3 T=W(Xb)^2; p4 Xa=Xb*T;
    // p5 Pb=Pa*W(Xa); p6 T=W(Xa)^2; p7 Xb=Xa*T; p8 Pa=Pb*W(Xb)   (P4 -> Pa)
    const float* Al[9] = {Xa, Xa, Xa, Xb, Xb, Pa, Xa, Xa, Pb};
    const float* Bl[9] = {Xa, T,  Xb, Xb, T,  Xa, Xa, T,  Xb};
    float*       Cl[9] = {T,  Xb, Pa, T,  Xa, Pb, T,  Xb, Pa};
    const int   TAl[9] = {1, 0, 1, 1, 0, 0, 1, 0, 0};
    const int   TBl[9] = {1, 0, 1, 1, 0, 1, 1, 0, 1};

    for (int p = 0; p < 9; ++p) {
        if (p) {
            __threadfence();
            grid.sync();
        }
        bmm_pass(Al[p] + off, Bl[p] + off, Cl[p] + off, TAl[p], TBl[p], tile, sm);
    }
}

// ---------------------------------------------------------------------------
// apply: out[b,s,e] = sum_d x[b,s,d]*wm[d,e] - corr[e],  corr[e]=sum_d m[d]*wm[d,e],
// wm = P*rsqrt(tr) (bf16, rs folded). v3 = round-1 proven shape (256 thr,
// 128x128 tile, 78.3KB LDS -> 2 blocks/CU) + next-step register prefetch +
// 16B-aligned b128 frag reads on both slabs (BSS=264, LTS=40) + corr trick.
// Grid (64 st, 2 nh, 16 b) x 256.
// ---------------------------------------------------------------------------
#define BSS 264
__global__ __launch_bounds__(256) void apply_kernel(const float* __restrict__ x,
                                                    const float* __restrict__ P,
                                                    const float* __restrict__ m,
                                                    const float* __restrict__ trbuf,
                                                    float* __restrict__ out) {
    const int st = blockIdx.x;
    const int nh = blockIdx.y;
    const int b  = blockIdx.z;
    const int s0 = st * 128;
    const int n0 = nh * 128;
    const float rs = trbuf[16 + b];
    const float* xb = x + (size_t)b * SS * DD;
    const float* Pb = P + (size_t)b * DD * DD;
    const float* mb = m + b * DD;
    float* ob = out + (size_t)b * SS * DD;

    __shared__ unsigned short Bs[128 * BSS];   // 67.6 KB
    __shared__ unsigned short As[128 * LTS];   // 10.2 KB
    __shared__ float corr[128];

    const int tid  = threadIdx.x;
    const int wave = tid >> 6;
    const int lane = tid & 63;
    const int lc = lane & 15, lq = lane >> 4;
    const int mrow0 = (wave & 1) * 64;
    const int ncol0 = (wave >> 1) * 64;

    {   // stage B once (rs folded in); wm[k][n]=wm[n][k] by symmetry
        const int r = tid >> 1, h = tid & 1;
        const float* prow = Pb + (size_t)(n0 + r) * DD + h * 128;
        unsigned short* brow = &Bs[r * BSS + h * 128];
#pragma unroll
        for (int i = 0; i < 32; ++i) {
            float4 pv = *(const float4*)(prow + i * 4);
            *(unsigned*)&brow[i * 4]     = pack2(pv.x * rs, pv.y * rs);
            *(unsigned*)&brow[i * 4 + 2] = pack2(pv.z * rs, pv.w * rs);
        }
    }
    __syncthreads();

    // rank-1 mean correction: corr[n] = sum_k m[k] * wm[k][n]  (from bf16 slab)
    if (tid < 128) {
        float s = 0.f;
        for (int k = 0; k < 256; ++k)
            s += mb[k] * bf2f(Bs[tid * BSS + k]);
        corr[tid] = s;
    }

    f32x4 acc[4][4];
#pragma unroll
    for (int mi = 0; mi < 4; ++mi)
#pragma unroll
        for (int ni = 0; ni < 4; ++ni) acc[mi][ni] = (f32x4){0.f, 0.f, 0.f, 0.f};

    const int r8 = tid >> 3;          // 0..31
    const int d4 = (tid & 7) * 4;     // k offset 0..28
    const float* xt = xb + (size_t)(s0 + r8) * DD + d4;

    float4 va[4], vb[4];

    auto LOAD = [&](float4* v, int t) {
#pragma unroll
        for (int i = 0; i < 4; ++i)
            v[i] = *(const float4*)(xt + (size_t)t * 32 + (size_t)i * 32 * DD);
    };
    auto STAGE = [&](const float4* v) {
#pragma unroll
        for (int i = 0; i < 4; ++i) {
            uint2 w;
            w.x = pack2(v[i].x, v[i].y);
            w.y = pack2(v[i].z, v[i].w);
            *(uint2*)&As[(r8 + i * 32) * LTS + d4] = w;
        }
    };
    auto COMPUTE = [&](int t) {
        const int k0 = t * 32;
        bf16x8 af[4], bfr[4];
#pragma unroll
        for (int mi = 0; mi < 4; ++mi)
            af[mi] = *(const bf16x8*)&As[(mrow0 + mi * 16 + lc) * LTS + lq * 8];
#pragma unroll
        for (int ni = 0; ni < 4; ++ni)
            bfr[ni] = *(const bf16x8*)&Bs[(ncol0 + ni * 16 + lc) * BSS + k0 + lq * 8];
#pragma unroll
        for (int mi = 0; mi < 4; ++mi)
#pragma unroll
            for (int ni = 0; ni < 4; ++ni)
                acc[mi][ni] = __builtin_amdgcn_mfma_f32_16x16x32_bf16(
                    af[mi], bfr[ni], acc[mi][ni], 0, 0, 0);
    };

    // K = 256 in 8 steps of 32; single As slab, loads issued one step ahead
    LOAD(va, 0);
#pragma unroll
    for (int tt = 0; tt < 4; ++tt) {
        const int t0 = 2 * tt;
        __syncthreads();                 // previous step's frag reads done
        STAGE(va);
        if (t0 + 1 < 8) LOAD(vb, t0 + 1);
        __syncthreads();
        COMPUTE(t0);
        __syncthreads();
        STAGE(vb);
        if (t0 + 2 < 8) LOAD(va, t0 + 2);
        __syncthreads();
        COMPUTE(t0 + 1);
    }

#pragma unroll
    for (int mi = 0; mi < 4; ++mi)
#pragma unroll
        for (int ni = 0; ni < 4; ++ni) {
            const int row = s0 + mrow0 + mi * 16 + lq * 4;
            const int col = n0 + ncol0 + ni * 16 + lc;
            const float cv = corr[ncol0 + ni * 16 + lc];
#pragma unroll
            for (int r = 0; r < 4; ++r)
                ob[(size_t)(row + r) * DD + col] = acc[mi][ni][r] - cv;
        }
}

extern "C" void kernel_launch(void* const* d_in, const int* in_sizes, int n_in,
                              void* d_out, int out_size, void* d_ws, size_t ws_size,
                              hipStream_t stream) {
    const float* x = (const float*)d_in[0];
    float* out = (float*)d_out;
    float* ws = (float*)d_ws;

    const size_t MAT = (size_t)BB * DD * DD;        // 1,048,576 floats
    float* partial = ws;                            // 8 * MAT = 32 MB
    float* sumx8 = partial + 8 * MAT;               // 32768
    float* m     = sumx8 + 8 * BB * DD;             // 4096
    float* trbuf = m + BB * DD;                     // 64
    float* Xa    = trbuf + 64;
    float* Xb    = Xa + MAT;
    float* T     = Xb + MAT;
    float* Pa    = T + MAT;
    float* Pb    = Pa + MAT;
    // total ~54.6 MB of workspace

    moment_kernel<<<dim3(8, 2, 16), 512, 0, stream>>>(x, partial, sumx8);
    stats_kernel<<<16, 256, 0, stream>>>(partial, sumx8, m, trbuf);
    sigman_kernel<<<dim3(256, 16), 256, 0, stream>>>(partial, m, trbuf, Xa);

    {   // Newton-Schulz chain: one cooperative launch, 9 passes, 8 grid syncs
        void* args[] = {&Xa, &Xb, &T, &Pa, &Pb};
        hipLaunchCooperativeKernel(ns_chain, dim3(256), dim3(512), args, 0, stream);
    }

    apply_kernel<<<dim3(64, 2, 16), 256, 0, stream>>>(x, Pa, m, trbuf, out);
}

// Round 5
// 379.116 us; speedup vs baseline: 2.6043x; 2.6043x over previous
//
#include <hip/hip_runtime.h>

#define BB 16
#define SS 8192
#define DD 256

typedef __attribute__((ext_vector_type(8))) short bf16x8;
typedef __attribute__((ext_vector_type(4))) short bf16x4;
typedef __attribute__((ext_vector_type(4))) float f32x4;

__device__ __forceinline__ unsigned short f2bf(float f) {
    union { float f; unsigned u; } v; v.f = f;
    unsigned r = v.u + 0x7FFFu + ((v.u >> 16) & 1u);   // round-to-nearest-even
    return (unsigned short)(r >> 16);
}
__device__ __forceinline__ float bf2f(unsigned short u) {
    union { unsigned u; float f; } cv; cv.u = (unsigned)u << 16; return cv.f;
}
__device__ __forceinline__ unsigned pack2(float a, float b) {
    return (unsigned)f2bf(a) | ((unsigned)f2bf(b) << 16);
}
// split w into hi+lo bf16 (residual ~2^-18 relative)
__device__ __forceinline__ void split_bf(float w, unsigned short& hi, unsigned short& lo) {
    hi = f2bf(w);
    lo = f2bf(w - bf2f(hi));
}

#define LTS 40   // slab row stride in shorts: 80B = 16B*5 -> aligned b128 frag reads

// ---------------------------------------------------------------------------
// moment: partial[kc][b][d][e] = sum_{s in kc-chunk} x[b,s,d]*x[b,s,e]  (bf16 MFMA)
// plus per-(kc,b) column sums written non-atomically to sumx8 (no memset needed).
// Grid (8 kc, 2 nh, 16 b) x 512 threads. 8 waves, double-buffered LDS slab,
// register prefetch 2 steps ahead, one barrier per K-step. (unchanged, passing)
// ---------------------------------------------------------------------------
__global__ __launch_bounds__(512) void moment_kernel(const float* __restrict__ x,
                                                     float* __restrict__ partial,
                                                     float* __restrict__ sumx8) {
    const int kc = blockIdx.x;
    const int nh = blockIdx.y;
    const int b  = blockIdx.z;
    const float* xb = x + ((size_t)b * SS + (size_t)kc * 1024) * DD;

    __shared__ unsigned short Lt0[256 * LTS];
    __shared__ unsigned short Lt1[256 * LTS];
    __shared__ float csh[8 * 256];

    const int tid  = threadIdx.x;
    const int wave = tid >> 6;
    const int lane = tid & 63;
    const int lc   = lane & 15;
    const int lq   = lane >> 4;

    const int mrow0 = (wave & 3) * 64;
    const int ncol0 = nh * 128 + (wave >> 2) * 64;

    const int sg = tid >> 6;
    const int dg = tid & 63;
    const float* xt = xb + (size_t)(sg * 4) * DD + dg;

    f32x4 acc[4][4];
#pragma unroll
    for (int mi = 0; mi < 4; ++mi)
#pragma unroll
        for (int ni = 0; ni < 4; ++ni) acc[mi][ni] = (f32x4){0.f, 0.f, 0.f, 0.f};
    float cs[4] = {0.f, 0.f, 0.f, 0.f};

    float va[16], vb[16];

    auto LOAD = [&](float* v, int t) {
#pragma unroll
        for (int i = 0; i < 4; ++i)
#pragma unroll
            for (int j = 0; j < 4; ++j)
                v[i * 4 + j] = xt[(size_t)(t * 32 + i) * DD + 64 * j];
    };
    auto STAGE = [&](const float* v, unsigned short* Lw) {
        if (nh == 0) {
#pragma unroll
            for (int j = 0; j < 4; ++j)
                cs[j] += v[j] + v[4 + j] + v[8 + j] + v[12 + j];
        }
#pragma unroll
        for (int j = 0; j < 4; ++j) {
            uint2 w;
            w.x = pack2(v[j], v[4 + j]);
            w.y = pack2(v[8 + j], v[12 + j]);
            *(uint2*)&Lw[(dg + 64 * j) * LTS + sg * 4] = w;
        }
    };
    auto COMPUTE = [&](const unsigned short* Lr) {
        bf16x8 af[4], bfr[4];
#pragma unroll
        for (int mi = 0; mi < 4; ++mi)
            af[mi] = *(const bf16x8*)&Lr[(mrow0 + mi * 16 + lc) * LTS + lq * 8];
#pragma unroll
        for (int ni = 0; ni < 4; ++ni)
            bfr[ni] = *(const bf16x8*)&Lr[(ncol0 + ni * 16 + lc) * LTS + lq * 8];
#pragma unroll
        for (int mi = 0; mi < 4; ++mi)
#pragma unroll
            for (int ni = 0; ni < 4; ++ni)
                acc[mi][ni] = __builtin_amdgcn_mfma_f32_16x16x32_bf16(
                    af[mi], bfr[ni], acc[mi][ni], 0, 0, 0);
    };

    LOAD(va, 0);
    STAGE(va, Lt0);
    LOAD(vb, 1);
    __syncthreads();

    for (int tt = 0; tt < 16; ++tt) {
        const int t0 = 2 * tt;
        STAGE(vb, Lt1);
        if (t0 < 30) LOAD(va, t0 + 2);
        COMPUTE(Lt0);
        __syncthreads();
        if (t0 + 1 < 31) STAGE(va, Lt0);
        if (t0 + 1 < 30) LOAD(vb, t0 + 3);
        COMPUTE(Lt1);
        __syncthreads();
    }

    float* pp = partial + (size_t)(kc * 16 + b) * DD * DD;
#pragma unroll
    for (int mi = 0; mi < 4; ++mi)
#pragma unroll
        for (int ni = 0; ni < 4; ++ni) {
            const int row = mrow0 + mi * 16 + lq * 4;
            const int col = ncol0 + ni * 16 + lc;
#pragma unroll
            for (int r = 0; r < 4; ++r)
                pp[(size_t)(row + r) * DD + col] = acc[mi][ni][r];
        }

    if (nh == 0) {
        __syncthreads();
#pragma unroll
        for (int j = 0; j < 4; ++j) csh[sg * 256 + dg + 64 * j] = cs[j];
        __syncthreads();
        if (tid < 256) {
            float t0 = 0.f;
#pragma unroll
            for (int g = 0; g < 8; ++g) t0 += csh[g * 256 + tid];
            sumx8[(size_t)(kc * 16 + b) * DD + tid] = t0;
        }
    }
}

// ---------------------------------------------------------------------------
// stats (unchanged)
// ---------------------------------------------------------------------------
__global__ __launch_bounds__(256) void stats_kernel(const float* __restrict__ partial,
                                                    const float* __restrict__ sumx8,
                                                    float* __restrict__ m,
                                                    float* __restrict__ trbuf) {
    const int b = blockIdx.x;
    const int d = threadIdx.x;
    float sx = 0.f;
#pragma unroll
    for (int kc = 0; kc < 8; ++kc)
        sx += sumx8[(size_t)(kc * 16 + b) * DD + d];
    const float mean = sx * (1.0f / (float)SS);
    m[b * DD + d] = mean;
    float ds = 0.f;
#pragma unroll
    for (int kc = 0; kc < 8; ++kc)
        ds += partial[((size_t)(kc * 16 + b) * DD + d) * DD + d];
    const float diag = (ds - (float)SS * mean * mean) * (1.0f / (float)(SS - 1));
    __shared__ float red[256];
    red[d] = diag;
    __syncthreads();
    for (int off = 128; off > 0; off >>= 1) {
        if (d < off) red[d] += red[d + off];
        __syncthreads();
    }
    if (d == 0) {
        const float tr = red[0];
        trbuf[b]      = tr;
        trbuf[16 + b] = rsqrtf(tr);
        trbuf[32 + b] = 1.0f / tr;
    }
}

// ---------------------------------------------------------------------------
// sigman (unchanged)
// ---------------------------------------------------------------------------
__global__ __launch_bounds__(256) void sigman_kernel(const float* __restrict__ partial,
                                                     const float* __restrict__ m,
                                                     const float* __restrict__ trbuf,
                                                     float* __restrict__ Xa) {
    const int b = blockIdx.y;
    const int d = blockIdx.x;
    const int e = threadIdx.x;
    const float itr = trbuf[32 + b];
    const float md = m[b * DD + d];
    const float me = m[b * DD + e];
    float s = 0.f;
#pragma unroll
    for (int kc = 0; kc < 8; ++kc)
        s += partial[((size_t)(kc * 16 + b) * DD + d) * DD + e];
    Xa[(size_t)b * DD * DD + (size_t)d * DD + e] =
        (s - (float)SS * md * me) * (1.0f / (float)(SS - 1)) * itr;
}

// ---------------------------------------------------------------------------
// Batched 256^3 matmul via MFMA with split-bf16 (hi+lo) fp32 emulation:
// C = opA(A) @ opB(B), op = identity or W(X) = 1.5I - 0.5X (runtime flag).
// Round-3 proven kernel; only change: both prologue chunk loads issued before
// the first STAGE so chunk-1 latency hides under chunk-0 staging VALU.
// Stream-launched (cooperative grid.sync measured ~72us/sync in round 4 --
// device-scope L2 flush across 8 XCDs -- so inter-kernel deps stay as launches).
// ---------------------------------------------------------------------------
#define BTS 72   // slab stride in shorts: 144B = 16B*9 -> aligned b128, 2-way banks
__global__ __launch_bounds__(256) void bmm_mfma(
    const float* __restrict__ A0, const float* __restrict__ B0, float* __restrict__ C0,
    int ta0, int tb0,
    const float* __restrict__ A1, const float* __restrict__ B1, float* __restrict__ C1,
    int ta1, int tb1) {
    const int by  = blockIdx.y;
    const int set = by >> 4;
    const int bb  = by & 15;
    const float* Ag = (set ? A1 : A0) + (size_t)bb * DD * DD;
    const float* Bg = (set ? B1 : B0) + (size_t)bb * DD * DD;
    float*       Cg = (set ? C1 : C0) + (size_t)bb * DD * DD;
    const int TA = set ? ta1 : ta0;
    const int TB = set ? tb1 : tb0;

    const int m0 = (blockIdx.x >> 2) * 64;
    const int n0 = (blockIdx.x & 3) * 64;

    __shared__ unsigned short Ahi[2][64 * BTS];   // 4 slabs x 2 bufs = 72 KB total
    __shared__ unsigned short Alo[2][64 * BTS];
    __shared__ unsigned short Bhi[2][64 * BTS];
    __shared__ unsigned short Blo[2][64 * BTS];

    const int tid  = threadIdx.x;
    const int wave = tid >> 6;
    const int lane = tid & 63;
    const int lc = lane & 15, lq = lane >> 4;
    const int mrow0 = (wave & 1) * 32;
    const int ncol0 = (wave >> 1) * 32;

    const int r  = tid >> 2;          // 0..63 : slab row
    const int kl = (tid & 3) * 4;     // k offset within 16-float group
    const float* Arow = Ag + (size_t)(m0 + r) * DD + kl;
    const float* Brow = Bg + (size_t)(n0 + r) * DD + kl;

    f32x4 acc[2][2];
#pragma unroll
    for (int mi = 0; mi < 2; ++mi)
#pragma unroll
        for (int ni = 0; ni < 2; ++ni) acc[mi][ni] = (f32x4){0.f, 0.f, 0.f, 0.f};

    float4 va0[4], vb0[4], va1[4], vb1[4];

    auto LOADC = [&](float4* va, float4* vb, int c) {
#pragma unroll
        for (int i = 0; i < 4; ++i) va[i] = *(const float4*)(Arow + c * 64 + i * 16);
#pragma unroll
        for (int i = 0; i < 4; ++i) vb[i] = *(const float4*)(Brow + c * 64 + i * 16);
    };
    auto STAGE_SIDE = [&](const float4* v, unsigned short* Shi, unsigned short* Slo,
                          int c, int gmn, int tflag) {
#pragma unroll
        for (int i = 0; i < 4; ++i) {
            float xv[4] = {v[i].x, v[i].y, v[i].z, v[i].w};
            unsigned short h[4], l[4];
#pragma unroll
            for (int j = 0; j < 4; ++j) {
                float wv = xv[j];
                if (tflag) {
                    const int gk = c * 64 + kl + i * 16 + j;
                    wv = ((gk == gmn) ? 1.5f : 0.0f) - 0.5f * wv;
                }
                split_bf(wv, h[j], l[j]);
            }
            unsigned short* ph = &Shi[r * BTS + kl + i * 16];
            *(unsigned*)&ph[0] = (unsigned)h[0] | ((unsigned)h[1] << 16);
            *(unsigned*)&ph[2] = (unsigned)h[2] | ((unsigned)h[3] << 16);
            unsigned short* pl = &Slo[r * BTS + kl + i * 16];
            *(unsigned*)&pl[0] = (unsigned)l[0] | ((unsigned)l[1] << 16);
            *(unsigned*)&pl[2] = (unsigned)l[2] | ((unsigned)l[3] << 16);
        }
    };
    auto STAGE = [&](const float4* va, const float4* vb, int c, int buf) {
        STAGE_SIDE(va, Ahi[buf], Alo[buf], c, m0 + r, TA);
        STAGE_SIDE(vb, Bhi[buf], Blo[buf], c, n0 + r, TB);
    };
    auto COMPUTE = [&](int buf) {
#pragma unroll
        for (int ks = 0; ks < 2; ++ks) {
            bf16x8 ah[2], al[2], bh[2], bl[2];
#pragma unroll
            for (int mi = 0; mi < 2; ++mi) {
                const int off = (mrow0 + mi * 16 + lc) * BTS + ks * 32 + lq * 8;
                ah[mi] = *(const bf16x8*)&Ahi[buf][off];
                al[mi] = *(const bf16x8*)&Alo[buf][off];
            }
#pragma unroll
            for (int ni = 0; ni < 2; ++ni) {
                const int off = (ncol0 + ni * 16 + lc) * BTS + ks * 32 + lq * 8;
                bh[ni] = *(const bf16x8*)&Bhi[buf][off];
                bl[ni] = *(const bf16x8*)&Blo[buf][off];
            }
#pragma unroll
            for (int mi = 0; mi < 2; ++mi)
#pragma unroll
                for (int ni = 0; ni < 2; ++ni) {
                    acc[mi][ni] = __builtin_amdgcn_mfma_f32_16x16x32_bf16(
                        al[mi], bh[ni], acc[mi][ni], 0, 0, 0);
                    acc[mi][ni] = __builtin_amdgcn_mfma_f32_16x16x32_bf16(
                        ah[mi], bl[ni], acc[mi][ni], 0, 0, 0);
                    acc[mi][ni] = __builtin_amdgcn_mfma_f32_16x16x32_bf16(
                        ah[mi], bh[ni], acc[mi][ni], 0, 0, 0);
                }
        }
    };

    // 4 K-chunks of 64, double-buffered, prefetch 2 ahead (both issued upfront)
    LOADC(va0, vb0, 0);
    LOADC(va1, vb1, 1);
    STAGE(va0, vb0, 0, 0);
    __syncthreads();
#pragma unroll
    for (int cc = 0; cc < 2; ++cc) {
        const int c0 = 2 * cc;
        STAGE(va1, vb1, c0 + 1, 1);
        if (c0 + 2 < 4) LOADC(va0, vb0, c0 + 2);
        COMPUTE(0);
        __syncthreads();
        if (c0 + 2 < 4) STAGE(va0, vb0, c0 + 2, 0);
        if (c0 + 3 < 4) LOADC(va1, vb1, c0 + 3);
        COMPUTE(1);
        __syncthreads();
    }

#pragma unroll
    for (int mi = 0; mi < 2; ++mi)
#pragma unroll
        for (int ni = 0; ni < 2; ++ni) {
            const int row = m0 + mrow0 + mi * 16 + lq * 4;
            const int col = n0 + ncol0 + ni * 16 + lc;
#pragma unroll
            for (int rr = 0; rr < 4; ++rr)
                Cg[(size_t)(row + rr) * DD + col] = acc[mi][ni][rr];
        }
}

// ---------------------------------------------------------------------------
// apply: out[b,s,e] = sum_d x[b,s,d]*wm[d,e] - corr[e],  corr[e]=sum_d m[d]*wm[d,e],
// wm = P*rsqrt(tr) (bf16, rs folded). Round-1 measured shape (256 thr, 128x128
// tile, 4 waves, ~78KB LDS -> 2 blocks/CU) + LTS40/BSS264 aligned b128 frag
// reads + one-step register prefetch + corr trick (proven in rounds 3/4).
// Grid (64 st, 2 nh, 16 b) x 256.
// ---------------------------------------------------------------------------
#define BSS 264
__global__ __launch_bounds__(256) void apply_kernel(const float* __restrict__ x,
                                                    const float* __restrict__ P,
                                                    const float* __restrict__ m,
                                                    const float* __restrict__ trbuf,
                                                    float* __restrict__ out) {
    const int st = blockIdx.x;
    const int nh = blockIdx.y;
    const int b  = blockIdx.z;
    const int s0 = st * 128;
    const int n0 = nh * 128;
    const float rs = trbuf[16 + b];
    const float* xb = x + (size_t)b * SS * DD;
    const float* Pb = P + (size_t)b * DD * DD;
    const float* mb = m + b * DD;
    float* ob = out + (size_t)b * SS * DD;

    __shared__ unsigned short Bs[128 * BSS];   // 67.6 KB
    __shared__ unsigned short As[128 * LTS];   // 10.2 KB
    __shared__ float corr[128];

    const int tid  = threadIdx.x;
    const int wave = tid >> 6;
    const int lane = tid & 63;
    const int lc = lane & 15, lq = lane >> 4;
    const int mrow0 = (wave & 1) * 64;
    const int ncol0 = (wave >> 1) * 64;

    {   // stage B once (rs folded in); wm[k][n]=wm[n][k] by symmetry
        const int r = tid >> 1, h = tid & 1;
        const float* prow = Pb + (size_t)(n0 + r) * DD + h * 128;
        unsigned short* brow = &Bs[r * BSS + h * 128];
#pragma unroll
        for (int i = 0; i < 32; ++i) {
            float4 pv = *(const float4*)(prow + i * 4);
            *(unsigned*)&brow[i * 4]     = pack2(pv.x * rs, pv.y * rs);
            *(unsigned*)&brow[i * 4 + 2] = pack2(pv.z * rs, pv.w * rs);
        }
    }
    __syncthreads();

    // rank-1 mean correction: corr[n] = sum_k m[k] * wm[k][n]  (from bf16 slab)
    if (tid < 128) {
        float s = 0.f;
        for (int k = 0; k < 256; ++k)
            s += mb[k] * bf2f(Bs[tid * BSS + k]);
        corr[tid] = s;
    }

    f32x4 acc[4][4];
#pragma unroll
    for (int mi = 0; mi < 4; ++mi)
#pragma unroll
        for (int ni = 0; ni < 4; ++ni) acc[mi][ni] = (f32x4){0.f, 0.f, 0.f, 0.f};

    const int r8 = tid >> 3;          // 0..31
    const int d4 = (tid & 7) * 4;     // k offset 0..28
    const float* xt = xb + (size_t)(s0 + r8) * DD + d4;

    float4 va[4], vb[4];

    auto LOAD = [&](float4* v, int t) {
#pragma unroll
        for (int i = 0; i < 4; ++i)
            v[i] = *(const float4*)(xt + (size_t)t * 32 + (size_t)i * 32 * DD);
    };
    auto STAGE = [&](const float4* v) {
#pragma unroll
        for (int i = 0; i < 4; ++i) {
            uint2 w;
            w.x = pack2(v[i].x, v[i].y);
            w.y = pack2(v[i].z, v[i].w);
            *(uint2*)&As[(r8 + i * 32) * LTS + d4] = w;
        }
    };
    auto COMPUTE = [&](int t) {
        const int k0 = t * 32;
        bf16x8 af[4], bfr[4];
#pragma unroll
        for (int mi = 0; mi < 4; ++mi)
            af[mi] = *(const bf16x8*)&As[(mrow0 + mi * 16 + lc) * LTS + lq * 8];
#pragma unroll
        for (int ni = 0; ni < 4; ++ni)
            bfr[ni] = *(const bf16x8*)&Bs[(ncol0 + ni * 16 + lc) * BSS + k0 + lq * 8];
#pragma unroll
        for (int mi = 0; mi < 4; ++mi)
#pragma unroll
            for (int ni = 0; ni < 4; ++ni)
                acc[mi][ni] = __builtin_amdgcn_mfma_f32_16x16x32_bf16(
                    af[mi], bfr[ni], acc[mi][ni], 0, 0, 0);
    };

    // K = 256 in 8 steps of 32; single As slab, 2 barriers/step (round-1 shape),
    // next step's global loads issued between STAGE and COMPUTE.
    LOAD(va, 0);
#pragma unroll
    for (int tt = 0; tt < 4; ++tt) {
        const int t0 = 2 * tt;
        __syncthreads();                 // previous step's frag reads done
        STAGE(va);
        if (t0 + 1 < 8) LOAD(vb, t0 + 1);
        __syncthreads();
        COMPUTE(t0);
        __syncthreads();
        STAGE(vb);
        if (t0 + 2 < 8) LOAD(va, t0 + 2);
        __syncthreads();
        COMPUTE(t0 + 1);
    }

#pragma unroll
    for (int mi = 0; mi < 4; ++mi)
#pragma unroll
        for (int ni = 0; ni < 4; ++ni) {
            const int row = s0 + mrow0 + mi * 16 + lq * 4;
            const int col = n0 + ncol0 + ni * 16 + lc;
            const float cv = corr[ncol0 + ni * 16 + lc];
#pragma unroll
            for (int r = 0; r < 4; ++r)
                ob[(size_t)(row + r) * DD + col] = acc[mi][ni][r] - cv;
        }
}

extern "C" void kernel_launch(void* const* d_in, const int* in_sizes, int n_in,
                              void* d_out, int out_size, void* d_ws, size_t ws_size,
                              hipStream_t stream) {
    const float* x = (const float*)d_in[0];
    float* out = (float*)d_out;
    float* ws = (float*)d_ws;

    const size_t MAT = (size_t)BB * DD * DD;        // 1,048,576 floats
    float* partial = ws;                            // 8 * MAT = 32 MB
    float* sumx8 = partial + 8 * MAT;               // 32768
    float* m     = sumx8 + 8 * BB * DD;             // 4096
    float* trbuf = m + BB * DD;                     // 64
    float* Xa    = trbuf + 64;
    float* Xb    = Xa + MAT;
    float* T     = Xb + MAT;
    float* Pa    = T + MAT;
    float* Pb    = Pa + MAT;
    // total ~54.6 MB of workspace

    moment_kernel<<<dim3(8, 2, 16), 512, 0, stream>>>(x, partial, sumx8);
    stats_kernel<<<16, 256, 0, stream>>>(partial, sumx8, m, trbuf);
    sigman_kernel<<<dim3(256, 16), 256, 0, stream>>>(partial, m, trbuf, Xa);

    // Newton-Schulz: X_{k+1} = X_k W_k^2, P_{k+1} = P_k W_k, W_k = 1.5I - 0.5 X_k
    // (all symmetric, commuting). Independent products fused 2-per-launch.
    bmm_mfma<<<dim3(16, 16), 256, 0, stream>>>(Xa, Xa, T, 1, 1,
                                               Xa, Xa, T, 1, 1);   // T  = W0^2
    bmm_mfma<<<dim3(16, 16), 256, 0, stream>>>(Xa, T, Xb, 0, 0,
                                               Xa, T, Xb, 0, 0);   // X1 = X0*T
    bmm_mfma<<<dim3(16, 32), 256, 0, stream>>>(Xa, Xb, Pa, 1, 1,   // P2 = W0*W1
                                               Xb, Xb, T, 1, 1);   // T  = W1^2
    bmm_mfma<<<dim3(16, 16), 256, 0, stream>>>(Xb, T, Xa, 0, 0,
                                               Xb, T, Xa, 0, 0);   // X2 = X1*T
    bmm_mfma<<<dim3(16, 32), 256, 0, stream>>>(Pa, Xa, Pb, 0, 1,   // P3 = P2*W2
                                               Xa, Xa, T, 1, 1);   // T  = W2^2
    bmm_mfma<<<dim3(16, 16), 256, 0, stream>>>(Xa, T, Xb, 0, 0,
                                               Xa, T, Xb, 0, 0);   // X3 = X2*T
    bmm_mfma<<<dim3(16, 16), 256, 0, stream>>>(Pb, Xb, Pa, 0, 1,
                                               Pb, Xb, Pa, 0, 1);  // P4 = P3*W3

    apply_kernel<<<dim3(64, 2, 16), 256, 0, stream>>>(x, Pa, m, trbuf, out);
}